// Round 10
// baseline (139.988 us; speedup 1.0000x reference)
//
#include <hip/hip_runtime.h>
#include <hip/hip_fp16.h>

#define N_NODES 50000
#define N_EDGES 800000
#define N_GRAPHS 256
#define D_FEAT 96
#define HIDDEN 32

#define NB 782        // bins: bin = dst >> 6 (64 nodes/bin); 782*64 >= 50000
#define BN 64         // nodes per bin
#define PB 500        // partition blocks
#define PCHUNK 1600   // 500 * 1600 = 800000 exactly
#define SEGCAP 16     // per-(block,bin) capacity (mean 2.05, P(>=16)~6e-10/cell)
#define NLOAD 8       // ceil(PB*SEGCAP/1024) staged loads in k_agg
#define GWIN 4        // pooled-graph LDS window per 64-node bin
#define LCAP2 2048    // per-bin sorted list capacity (mean ~1276 padded, >20 sigma)
#define XT 64         // nodes per xw1 tile block
#define XBLK 782      // ceil(50000/64)
#define XS_STRIDE 97  // padded LDS row stride (conflict-free lane=node reads)
#define DUMMY_NODE N_NODES   // extra zeroed y16 row for list padding

// ---------------------------------------------------------------------------
// Kernel A: blocks 0..PB-1 partition edges (int4, ILP-4) into per-(block,bin)
// segments; blocks PB.. compute y16 = fp16(x @ W1) + init chores.
// (verified structure; only NB/SEGCAP constants changed)
__global__ void __launch_bounds__(256)
k_front(const float* __restrict__ x, const float* __restrict__ W1,
        __half* __restrict__ y16,
        const int* __restrict__ src, const int* __restrict__ dst,
        unsigned int* __restrict__ binned, unsigned short* __restrict__ cnt,
        float* __restrict__ sums, float* __restrict__ counts) {
    __shared__ __align__(16) char smem[26656];   // union: hcur | xs
    int blk = blockIdx.x;
    int tid = threadIdx.x;
    if (blk < PB) {
        int* hcur = (int*)smem;                  // NB ints = 3128 B
        for (int i = tid; i < NB; i += 256) hcur[i] = 0;
        __syncthreads();

        int e0 = blk * PCHUNK, e1 = e0 + PCHUNK;
        for (int it = 0; it < PCHUNK; it += 1024) {
            int e = e0 + it + tid * 4;
            if (e < e1) {
                int4 s4 = *(const int4*)&src[e];
                int4 d4 = *(const int4*)&dst[e];
                unsigned w0 = (unsigned)s4.x | ((unsigned)(d4.x & 255) << 16);
                unsigned w1 = (unsigned)s4.y | ((unsigned)(d4.y & 255) << 16);
                unsigned w2 = (unsigned)s4.z | ((unsigned)(d4.z & 255) << 16);
                unsigned w3 = (unsigned)s4.w | ((unsigned)(d4.w & 255) << 16);
                int b0 = d4.x >> 6, b1 = d4.y >> 6, b2 = d4.z >> 6, b3 = d4.w >> 6;
                int p0 = atomicAdd(&hcur[b0], 1);
                int p1 = atomicAdd(&hcur[b1], 1);
                int p2 = atomicAdd(&hcur[b2], 1);
                int p3 = atomicAdd(&hcur[b3], 1);
                if (p0 < SEGCAP) binned[((size_t)b0 * PB + blk) * SEGCAP + p0] = w0;
                if (p1 < SEGCAP) binned[((size_t)b1 * PB + blk) * SEGCAP + p1] = w1;
                if (p2 < SEGCAP) binned[((size_t)b2 * PB + blk) * SEGCAP + p2] = w2;
                if (p3 < SEGCAP) binned[((size_t)b3 * PB + blk) * SEGCAP + p3] = w3;
            }
        }
        __syncthreads();

        for (int i = tid; i < NB; i += 256) {
            int c = hcur[i]; if (c > SEGCAP) c = SEGCAP;
            cnt[i * PB + blk] = (unsigned short)c;
        }
    } else {
        float* xs = (float*)smem;                   // XT * XS_STRIDE floats
        int xb = blk - PB;
        int n0 = xb * XT;
        int nn = N_NODES - n0; if (nn > XT) nn = XT;

        // folded init chores (these blocks run before k_agg)
        int gid = xb * 256 + tid;
        if (gid < N_GRAPHS * HIDDEN) sums[gid] = 0.f;
        if (gid < N_GRAPHS) counts[gid] = 0.f;
        if (xb == 0 && tid < HIDDEN)
            y16[(size_t)DUMMY_NODE * HIDDEN + tid] = __float2half(0.f);

        const float4* xsrc = (const float4*)(x + (size_t)n0 * D_FEAT);
        int nf4 = nn * (D_FEAT / 4);                // up to 1536
        for (int idx = tid; idx < nf4; idx += 256) {
            int ln = (idx * 2731) >> 16;            // idx / 24 for idx < 1536
            int k4 = idx - ln * 24;
            float4 v = xsrc[idx];
            float* dp = &xs[ln * XS_STRIDE + k4 * 4];
            dp[0] = v.x; dp[1] = v.y; dp[2] = v.z; dp[3] = v.w;
        }
        __syncthreads();

        int lane = tid & 63;                        // node within tile
        int f0 = (tid >> 6) << 3;                   // wave-uniform feature base
        f0 = __builtin_amdgcn_readfirstlane(f0);    // force SGPR

        if (lane < nn) {
            const float* xr = &xs[lane * XS_STRIDE];
            const float4* W1v = (const float4*)W1;  // row k = 8 float4s
            float acc[8];
#pragma unroll
            for (int j = 0; j < 8; ++j) acc[j] = 0.f;
#pragma unroll
            for (int k = 0; k < D_FEAT; ++k) {
                float xv = xr[k];                   // LDS, conflict-free (stride 97)
                float4 wa = W1v[k * 8 + (f0 >> 2)];
                float4 wb = W1v[k * 8 + (f0 >> 2) + 1];
                acc[0] = fmaf(xv, wa.x, acc[0]);
                acc[1] = fmaf(xv, wa.y, acc[1]);
                acc[2] = fmaf(xv, wa.z, acc[2]);
                acc[3] = fmaf(xv, wa.w, acc[3]);
                acc[4] = fmaf(xv, wb.x, acc[4]);
                acc[5] = fmaf(xv, wb.y, acc[5]);
                acc[6] = fmaf(xv, wb.z, acc[6]);
                acc[7] = fmaf(xv, wb.w, acc[7]);
            }
            __half2 h01 = __floats2half2_rn(acc[0], acc[1]);
            __half2 h23 = __floats2half2_rn(acc[2], acc[3]);
            __half2 h45 = __floats2half2_rn(acc[4], acc[5]);
            __half2 h67 = __floats2half2_rn(acc[6], acc[7]);
            float4 pack;
            pack.x = __uint_as_float(*(const unsigned*)&h01);
            pack.y = __uint_as_float(*(const unsigned*)&h23);
            pack.z = __uint_as_float(*(const unsigned*)&h45);
            pack.w = __uint_as_float(*(const unsigned*)&h67);
            *(float4*)&y16[(size_t)(n0 + lane) * HIDDEN + f0] = pack;  // 16B/lane
        }
    }
}

// ---------------------------------------------------------------------------
// Kernel B (64-node bins): histogram + counting-sort DIRECTLY from the staged
// registers (no 512-scan, no LDS pack list), wave64-shfl node scan, then the
// verified pipelined gather -> MLP -> pool. ~6 barriers total.
__global__ void __launch_bounds__(1024)
k_agg(const unsigned int* __restrict__ binned, const unsigned short* __restrict__ cnt,
      const __half* __restrict__ y16, const int* __restrict__ batch,
      const float* __restrict__ b1, const float* __restrict__ W2,
      const float* __restrict__ b2,
      float* __restrict__ sums, float* __restrict__ counts) {
    __shared__ unsigned short list2[LCAP2];    // 4 KB node-sorted src (8-padded)
    __shared__ unsigned short cs[512];         // 1 KB (>=500 zero-padded)
    __shared__ unsigned int ncnt[BN];
    __shared__ unsigned int offs[BN + 1];
    __shared__ unsigned int cur[BN];
    __shared__ float w2s[HIDDEN * HIDDEN];     // 4 KB
    __shared__ float accs[GWIN * HIDDEN];      // 512 B
    __shared__ float cntsl[GWIN];

    int tid = threadIdx.x;
    int bin = blockIdx.x;

    if (tid < BN) ncnt[tid] = 0;
    w2s[tid] = W2[tid];                        // 1024 threads cover exactly
    if (tid < GWIN * HIDDEN) accs[tid] = 0.f;
    if (tid < GWIN) cntsl[tid] = 0.f;
    if (tid < 512)
        cs[tid] = (tid < PB) ? cnt[bin * PB + tid] : (unsigned short)0;

    // stage the bin's whole segment region into registers (8 loads in flight)
    const unsigned int* ebase = binned + (size_t)bin * PB * SEGCAP;
    unsigned u[NLOAD];
#pragma unroll
    for (int j = 0; j < NLOAD; ++j) {
        int idx = tid + j * 1024;
        u[j] = (idx < PB * SEGCAP) ? ebase[idx] : 0u;   // j<7 unconditional
    }
    __syncthreads();

    // per-node histogram directly from registers
#pragma unroll
    for (int j = 0; j < NLOAD; ++j) {
        int idx = tid + j * 1024;
        int s = idx >> 4;                      // SEGCAP = 16 (s<512; cs=0 pads)
        int i = idx & 15;
        if (i < (int)cs[s])
            atomicAdd(&ncnt[(u[j] >> 16) & 63], 1u);
    }
    __syncthreads();

    // 8-padded exclusive scan over 64 node counts: single wave64 shfl scan
    if (tid < BN) {
        unsigned pc = (ncnt[tid] + 7u) & ~7u;
        unsigned v = pc;
#pragma unroll
        for (int d = 1; d < BN; d <<= 1) {
            unsigned t = __shfl_up(v, d, 64);
            if (tid >= d) v += t;
        }
        offs[tid + 1] = v;
        cur[tid] = v - pc;                     // exclusive offset
    }
    if (tid == 0) offs[0] = 0;
    __syncthreads();

    // counting-sort placement directly from registers
#pragma unroll
    for (int j = 0; j < NLOAD; ++j) {
        int idx = tid + j * 1024;
        int s = idx >> 4;
        int i = idx & 15;
        if (i < (int)cs[s]) {
            unsigned p = u[j];
            unsigned pos = atomicAdd(&cur[(p >> 16) & 63], 1u);
            if (pos < LCAP2) list2[pos] = (unsigned short)(p & 0xFFFFu);
        }
    }
    __syncthreads();
    // pad each node's list to its 8-multiple with the dummy (zero) row
    if (tid < BN) {
        unsigned i0 = cur[tid], i1 = offs[tid + 1];
        for (unsigned i = i0; i < i1 && i < LCAP2; ++i)
            list2[i] = (unsigned short)DUMMY_NODE;
    }
    __syncthreads();

    int node0 = bin << 6;
    int nn = N_NODES - node0; if (nn > BN) nn = BN;   // last bin: 16
    int g = tid >> 5;      // group 0..31 (two per wave64)
    int f = tid & 31;      // feature lane
    int gfirst = batch[node0];

    for (int ln = g * 2; ln < g * 2 + 2; ++ln) {
        if (ln >= nn) break;
        int node = node0 + ln;
        float acc = __half2float(y16[(size_t)node * HIDDEN + f]);   // self term
        int j = offs[ln];
        int jend = offs[ln + 1]; if (jend > LCAP2) jend = LCAP2;    // both %8 == 0
        for (; j < jend; j += 8) {                 // pure 8-deep pipeline
            ushort4 qa = *(const ushort4*)&list2[j];
            ushort4 qb = *(const ushort4*)&list2[j + 4];
            float a0 = __half2float(y16[(size_t)qa.x * HIDDEN + f]);
            float a1 = __half2float(y16[(size_t)qa.y * HIDDEN + f]);
            float a2 = __half2float(y16[(size_t)qa.z * HIDDEN + f]);
            float a3 = __half2float(y16[(size_t)qa.w * HIDDEN + f]);
            float a4 = __half2float(y16[(size_t)qb.x * HIDDEN + f]);
            float a5 = __half2float(y16[(size_t)qb.y * HIDDEN + f]);
            float a6 = __half2float(y16[(size_t)qb.z * HIDDEN + f]);
            float a7 = __half2float(y16[(size_t)qb.w * HIDDEN + f]);
            acc += ((a0 + a1) + (a2 + a3)) + ((a4 + a5) + (a6 + a7));
        }

        float h1 = fmaxf(acc + b1[f], 0.f);
        float h2 = b2[f];
#pragma unroll
        for (int k = 0; k < HIDDEN; ++k)           // h1[k] via intra-group shuffle
            h2 = fmaf(__shfl(h1, k, 32), w2s[k * HIDDEN + f], h2);
        float h = fmaxf(h2, 0.f);

        int gr = batch[node];
        int b = gr - gfirst;
        if (b < GWIN) {
            atomicAdd(&accs[b * HIDDEN + f], h);
            if (f == 0) atomicAdd(&cntsl[b], 1.f);
        } else {
            atomicAdd(&sums[(size_t)gr * HIDDEN + f], h);
            if (f == 0) atomicAdd(&counts[gr], 1.f);
        }
    }
    __syncthreads();

    if (tid < GWIN * HIDDEN) {
        float v = accs[tid];
        if (v != 0.f) atomicAdd(&sums[(size_t)gfirst * HIDDEN + tid], v);
    }
    if (tid < GWIN) {
        float c = cntsl[tid];
        if (c != 0.f) atomicAdd(&counts[gfirst + tid], c);
    }
}

// ---------------------------------------------------------------------------
// Kernel C: out[g] = (sums[g]/max(counts[g],1)) @ Wc + bc
__global__ void k_out(const float* __restrict__ sums, const float* __restrict__ counts,
                      const float* __restrict__ Wc, const float* __restrict__ bc,
                      float* __restrict__ out) {
    int g = threadIdx.x;
    if (g >= N_GRAPHS) return;
    float inv = 1.f / fmaxf(counts[g], 1.f);
    float o0 = bc[0], o1 = bc[1];
#pragma unroll
    for (int k = 0; k < HIDDEN; ++k) {
        float p = sums[(size_t)g * HIDDEN + k] * inv;
        o0 = fmaf(p, Wc[k * 2 + 0], o0);
        o1 = fmaf(p, Wc[k * 2 + 1], o1);
    }
    out[g * 2 + 0] = o0;
    out[g * 2 + 1] = o1;
}

// ---------------------------------------------------------------------------
extern "C" void kernel_launch(void* const* d_in, const int* in_sizes, int n_in,
                              void* d_out, int out_size, void* d_ws, size_t ws_size,
                              hipStream_t stream) {
    const float* x     = (const float*)d_in[0];
    const int*   ei    = (const int*)d_in[1];   // [2, N_EDGES]: src row then dst row
    const int*   batch = (const int*)d_in[2];
    const float* W1    = (const float*)d_in[3];
    const float* b1    = (const float*)d_in[4];
    const float* W2    = (const float*)d_in[5];
    const float* b2    = (const float*)d_in[6];
    const float* Wc    = (const float*)d_in[7];
    const float* bc    = (const float*)d_in[8];
    float* out = (float*)d_out;

    // Workspace layout (byte offsets):
    //   0         sums    8192 f                 (32768 B)
    //   32768     counts  256 f                  (1024 B)
    //   33792     cnt     NB*PB u16              (782000 B) -> end 815792
    //   815792    binned  NB*PB*SEGCAP u32       (25024000 B) -> end 25839792
    //   25839792  y16     (N_NODES+1)*32 half    (3200064 B)   total ~29 MB
    char* ws = (char*)d_ws;
    float*          sums   = (float*)ws;
    float*          counts = (float*)(ws + 32768);
    unsigned short* cnt    = (unsigned short*)(ws + 33792);
    unsigned int*   binned = (unsigned int*)(ws + 815792);
    __half*         y16    = (__half*)(ws + 25839792);

    k_front<<<PB + XBLK, 256, 0, stream>>>(
        x, W1, y16, ei, ei + N_EDGES, binned, cnt, sums, counts);

    k_agg<<<NB, 1024, 0, stream>>>(binned, cnt, y16, batch,
                                   b1, W2, b2, sums, counts);

    k_out<<<1, 256, 0, stream>>>(sums, counts, Wc, bc, out);
}

// Round 11
// 133.403 us; speedup vs baseline: 1.0494x; 1.0494x over previous
//
#include <hip/hip_runtime.h>
#include <hip/hip_fp16.h>

#define N_NODES 50000
#define N_EDGES 800000
#define N_GRAPHS 256
#define D_FEAT 96
#define HIDDEN 32

#define NB 391        // bins: bin = dst >> 7 (128 nodes/bin); 391*128 >= 50000
#define BN 128        // nodes per bin
#define PB 250        // partition blocks
#define PCHUNK 3200   // 250 * 3200 = 800000 exactly
#define SEGCAP 32     // per-(block,bin) capacity (mean 8.2, P(>=32)~1.7e-10/cell)
#define NLOAD 8       // ceil(PB*SEGCAP/1024) staged loads in k_agg
#define GWIN 4        // pooled-graph LDS window per 128-node bin
#define LCAP2 3456    // per-bin sorted list capacity (mean ~2500 padded, >8 sigma)
#define XT 64         // nodes per xw1 tile block
#define XBLK 782      // ceil(50000/64)
#define XS_STRIDE 97  // padded LDS row stride (conflict-free lane=node reads)
#define DUMMY_NODE N_NODES   // extra zeroed y16 row for list padding

// ---------------------------------------------------------------------------
// Kernel A: blocks 0..PB-1 partition edges (int4, ILP-4) into per-(block,bin)
// segments keyed by 128-node bins; blocks PB.. compute y16 = fp16(x @ W1)
// with BOTH x-tile AND W1 staged in LDS -> inner loop is pure-LDS (no SMEM
// in loop; avoids the lgkmcnt(0) SMEM/LDS mixing serialization).
__global__ void __launch_bounds__(256)
k_front(const float* __restrict__ x, const float* __restrict__ W1,
        __half* __restrict__ y16,
        const int* __restrict__ src, const int* __restrict__ dst,
        unsigned int* __restrict__ binned, unsigned short* __restrict__ cnt,
        float* __restrict__ sums, float* __restrict__ counts) {
    __shared__ __align__(16) char smem[37120];   // union: hcur | xs+w1s
    int blk = blockIdx.x;
    int tid = threadIdx.x;
    if (blk < PB) {
        int* hcur = (int*)smem;                  // NB ints = 1564 B
        for (int i = tid; i < NB; i += 256) hcur[i] = 0;
        __syncthreads();

        int e0 = blk * PCHUNK, e1 = e0 + PCHUNK;
        for (int it = 0; it < PCHUNK; it += 1024) {
            int e = e0 + it + tid * 4;
            if (e < e1) {
                int4 s4 = *(const int4*)&src[e];
                int4 d4 = *(const int4*)&dst[e];
                unsigned w0 = (unsigned)s4.x | ((unsigned)(d4.x & 127) << 16);
                unsigned w1 = (unsigned)s4.y | ((unsigned)(d4.y & 127) << 16);
                unsigned w2 = (unsigned)s4.z | ((unsigned)(d4.z & 127) << 16);
                unsigned w3 = (unsigned)s4.w | ((unsigned)(d4.w & 127) << 16);
                int b0 = d4.x >> 7, b1 = d4.y >> 7, b2 = d4.z >> 7, b3 = d4.w >> 7;
                int p0 = atomicAdd(&hcur[b0], 1);
                int p1 = atomicAdd(&hcur[b1], 1);
                int p2 = atomicAdd(&hcur[b2], 1);
                int p3 = atomicAdd(&hcur[b3], 1);
                if (p0 < SEGCAP) binned[((size_t)b0 * PB + blk) * SEGCAP + p0] = w0;
                if (p1 < SEGCAP) binned[((size_t)b1 * PB + blk) * SEGCAP + p1] = w1;
                if (p2 < SEGCAP) binned[((size_t)b2 * PB + blk) * SEGCAP + p2] = w2;
                if (p3 < SEGCAP) binned[((size_t)b3 * PB + blk) * SEGCAP + p3] = w3;
            }
        }
        __syncthreads();

        for (int i = tid; i < NB; i += 256) {
            int c = hcur[i]; if (c > SEGCAP) c = SEGCAP;
            cnt[i * PB + blk] = (unsigned short)c;
        }
    } else {
        float* xs  = (float*)smem;                  // XT*XS_STRIDE f = 24832 B
        float* w1s = (float*)(smem + 24832);        // 96*32 f = 12288 B
        int xb = blk - PB;
        int n0 = xb * XT;
        int nn = N_NODES - n0; if (nn > XT) nn = XT;

        // folded init chores (these blocks run before k_agg)
        int gid = xb * 256 + tid;
        if (gid < N_GRAPHS * HIDDEN) sums[gid] = 0.f;
        if (gid < N_GRAPHS) counts[gid] = 0.f;
        if (xb == 0 && tid < HIDDEN)
            y16[(size_t)DUMMY_NODE * HIDDEN + tid] = __float2half(0.f);

        // stage W1 (768 float4, coalesced)
        for (int i = tid; i < (D_FEAT * HIDDEN) / 4; i += 256)
            ((float4*)w1s)[i] = ((const float4*)W1)[i];

        // stage x tile: nn rows, coalesced float4 stream
        const float4* xsrc = (const float4*)(x + (size_t)n0 * D_FEAT);
        int nf4 = nn * (D_FEAT / 4);                // up to 1536
        for (int idx = tid; idx < nf4; idx += 256) {
            int ln = (idx * 2731) >> 16;            // idx / 24 for idx < 1536
            int k4 = idx - ln * 24;
            float4 v = xsrc[idx];
            float* dp = &xs[ln * XS_STRIDE + k4 * 4];
            dp[0] = v.x; dp[1] = v.y; dp[2] = v.z; dp[3] = v.w;
        }
        __syncthreads();

        int lane = tid & 63;                        // node within tile
        int f0 = (tid >> 6) << 3;                   // wave-uniform feature base
        f0 = __builtin_amdgcn_readfirstlane(f0);    // force SGPR

        if (lane < nn) {
            const float* xr = &xs[lane * XS_STRIDE];
            float acc[8];
#pragma unroll
            for (int j = 0; j < 8; ++j) acc[j] = 0.f;
#pragma unroll
            for (int k = 0; k < D_FEAT; ++k) {
                float xv = xr[k];                   // LDS, conflict-free (stride 97)
                float4 wa = *(const float4*)&w1s[k * HIDDEN + f0];      // bcast
                float4 wb = *(const float4*)&w1s[k * HIDDEN + f0 + 4];  // bcast
                acc[0] = fmaf(xv, wa.x, acc[0]);
                acc[1] = fmaf(xv, wa.y, acc[1]);
                acc[2] = fmaf(xv, wa.z, acc[2]);
                acc[3] = fmaf(xv, wa.w, acc[3]);
                acc[4] = fmaf(xv, wb.x, acc[4]);
                acc[5] = fmaf(xv, wb.y, acc[5]);
                acc[6] = fmaf(xv, wb.z, acc[6]);
                acc[7] = fmaf(xv, wb.w, acc[7]);
            }
            __half2 h01 = __floats2half2_rn(acc[0], acc[1]);
            __half2 h23 = __floats2half2_rn(acc[2], acc[3]);
            __half2 h45 = __floats2half2_rn(acc[4], acc[5]);
            __half2 h67 = __floats2half2_rn(acc[6], acc[7]);
            float4 pack;
            pack.x = __uint_as_float(*(const unsigned*)&h01);
            pack.y = __uint_as_float(*(const unsigned*)&h23);
            pack.z = __uint_as_float(*(const unsigned*)&h45);
            pack.w = __uint_as_float(*(const unsigned*)&h67);
            *(float4*)&y16[(size_t)(n0 + lane) * HIDDEN + f0] = pack;  // 16B/lane
        }
    }
}

// ---------------------------------------------------------------------------
// Kernel B (128-node bins, 391 blocks): histogram + counting-sort DIRECTLY
// from the staged registers (r10-verified structure), 2-wave shfl scan,
// then the verified pipelined gather -> MLP -> pool. Stream = 12.5 MB total.
__global__ void __launch_bounds__(1024)
k_agg(const unsigned int* __restrict__ binned, const unsigned short* __restrict__ cnt,
      const __half* __restrict__ y16, const int* __restrict__ batch,
      const float* __restrict__ b1, const float* __restrict__ W2,
      const float* __restrict__ b2,
      float* __restrict__ sums, float* __restrict__ counts) {
    __shared__ unsigned short list2[LCAP2];    // 6.9 KB node-sorted src (8-padded)
    __shared__ unsigned short cs[256];         // 512 B (>=250 zero-padded)
    __shared__ unsigned int ncnt[BN];
    __shared__ unsigned int offs[BN + 1];
    __shared__ unsigned int cur[BN];
    __shared__ unsigned int wtot;
    __shared__ float w2s[HIDDEN * HIDDEN];     // 4 KB
    __shared__ float accs[GWIN * HIDDEN];      // 512 B
    __shared__ float cntsl[GWIN];

    int tid = threadIdx.x;
    int bin = blockIdx.x;

    if (tid < BN) ncnt[tid] = 0;
    w2s[tid] = W2[tid];                        // 1024 threads cover exactly
    if (tid < GWIN * HIDDEN) accs[tid] = 0.f;
    if (tid < GWIN) cntsl[tid] = 0.f;
    if (tid < 256)
        cs[tid] = (tid < PB) ? cnt[bin * PB + tid] : (unsigned short)0;

    // stage the bin's whole segment region into registers (8 loads in flight)
    const unsigned int* ebase = binned + (size_t)bin * PB * SEGCAP;
    unsigned u[NLOAD];
#pragma unroll
    for (int j = 0; j < NLOAD; ++j) {
        int idx = tid + j * 1024;
        u[j] = (idx < PB * SEGCAP) ? ebase[idx] : 0u;   // j<7 unconditional
    }
    __syncthreads();

    // per-node histogram directly from registers
#pragma unroll
    for (int j = 0; j < NLOAD; ++j) {
        int idx = tid + j * 1024;
        int s = idx >> 5;                      // SEGCAP = 32
        int i = idx & 31;
        if (idx < PB * SEGCAP && i < (int)cs[s])
            atomicAdd(&ncnt[u[j] >> 16], 1u);
    }
    __syncthreads();

    // 8-padded exclusive scan over 128 node counts: 2-wave shfl + handoff
    unsigned v = 0, pc = 0;
    if (tid < BN) {
        pc = (ncnt[tid] + 7u) & ~7u;
        v = pc;
#pragma unroll
        for (int d = 1; d < 64; d <<= 1) {
            unsigned t = __shfl_up(v, d, 64);
            if ((tid & 63) >= d) v += t;
        }
        if (tid == 63) wtot = v;
    }
    __syncthreads();
    if (tid < BN) {
        if (tid >= 64) v += wtot;
        offs[tid + 1] = v;
        cur[tid] = v - pc;                     // exclusive offset
    }
    if (tid == 0) offs[0] = 0;
    __syncthreads();

    // counting-sort placement directly from registers
#pragma unroll
    for (int j = 0; j < NLOAD; ++j) {
        int idx = tid + j * 1024;
        int s = idx >> 5;
        int i = idx & 31;
        if (idx < PB * SEGCAP && i < (int)cs[s]) {
            unsigned p = u[j];
            unsigned pos = atomicAdd(&cur[p >> 16], 1u);
            if (pos < LCAP2) list2[pos] = (unsigned short)(p & 0xFFFFu);
        }
    }
    __syncthreads();
    // pad each node's list to its 8-multiple with the dummy (zero) row
    if (tid < BN) {
        unsigned i0 = cur[tid], i1 = offs[tid + 1];
        for (unsigned i = i0; i < i1 && i < LCAP2; ++i)
            list2[i] = (unsigned short)DUMMY_NODE;
    }
    __syncthreads();

    int node0 = bin << 7;
    int nn = N_NODES - node0; if (nn > BN) nn = BN;   // last bin: 80
    int g = tid >> 5;      // group 0..31 (two per wave64)
    int f = tid & 31;      // feature lane
    int gfirst = batch[node0];

    for (int ln = g * 4; ln < g * 4 + 4; ++ln) {
        if (ln >= nn) break;
        int node = node0 + ln;
        float acc = __half2float(y16[(size_t)node * HIDDEN + f]);   // self term
        int j = offs[ln];
        int jend = offs[ln + 1]; if (jend > LCAP2) jend = LCAP2;    // both %8 == 0
        for (; j < jend; j += 8) {                 // pure 8-deep pipeline
            ushort4 qa = *(const ushort4*)&list2[j];
            ushort4 qb = *(const ushort4*)&list2[j + 4];
            float a0 = __half2float(y16[(size_t)qa.x * HIDDEN + f]);
            float a1 = __half2float(y16[(size_t)qa.y * HIDDEN + f]);
            float a2 = __half2float(y16[(size_t)qa.z * HIDDEN + f]);
            float a3 = __half2float(y16[(size_t)qa.w * HIDDEN + f]);
            float a4 = __half2float(y16[(size_t)qb.x * HIDDEN + f]);
            float a5 = __half2float(y16[(size_t)qb.y * HIDDEN + f]);
            float a6 = __half2float(y16[(size_t)qb.z * HIDDEN + f]);
            float a7 = __half2float(y16[(size_t)qb.w * HIDDEN + f]);
            acc += ((a0 + a1) + (a2 + a3)) + ((a4 + a5) + (a6 + a7));
        }

        float h1 = fmaxf(acc + b1[f], 0.f);
        float h2 = b2[f];
#pragma unroll
        for (int k = 0; k < HIDDEN; ++k)           // h1[k] via intra-group shuffle
            h2 = fmaf(__shfl(h1, k, 32), w2s[k * HIDDEN + f], h2);
        float h = fmaxf(h2, 0.f);

        int gr = batch[node];
        int b = gr - gfirst;
        if (b < GWIN) {
            atomicAdd(&accs[b * HIDDEN + f], h);
            if (f == 0) atomicAdd(&cntsl[b], 1.f);
        } else {
            atomicAdd(&sums[(size_t)gr * HIDDEN + f], h);
            if (f == 0) atomicAdd(&counts[gr], 1.f);
        }
    }
    __syncthreads();

    if (tid < GWIN * HIDDEN) {
        float vv = accs[tid];
        if (vv != 0.f) atomicAdd(&sums[(size_t)gfirst * HIDDEN + tid], vv);
    }
    if (tid < GWIN) {
        float c = cntsl[tid];
        if (c != 0.f) atomicAdd(&counts[gfirst + tid], c);
    }
}

// ---------------------------------------------------------------------------
// Kernel C: out[g] = (sums[g]/max(counts[g],1)) @ Wc + bc
__global__ void k_out(const float* __restrict__ sums, const float* __restrict__ counts,
                      const float* __restrict__ Wc, const float* __restrict__ bc,
                      float* __restrict__ out) {
    int g = threadIdx.x;
    if (g >= N_GRAPHS) return;
    float inv = 1.f / fmaxf(counts[g], 1.f);
    float o0 = bc[0], o1 = bc[1];
#pragma unroll
    for (int k = 0; k < HIDDEN; ++k) {
        float p = sums[(size_t)g * HIDDEN + k] * inv;
        o0 = fmaf(p, Wc[k * 2 + 0], o0);
        o1 = fmaf(p, Wc[k * 2 + 1], o1);
    }
    out[g * 2 + 0] = o0;
    out[g * 2 + 1] = o1;
}

// ---------------------------------------------------------------------------
extern "C" void kernel_launch(void* const* d_in, const int* in_sizes, int n_in,
                              void* d_out, int out_size, void* d_ws, size_t ws_size,
                              hipStream_t stream) {
    const float* x     = (const float*)d_in[0];
    const int*   ei    = (const int*)d_in[1];   // [2, N_EDGES]: src row then dst row
    const int*   batch = (const int*)d_in[2];
    const float* W1    = (const float*)d_in[3];
    const float* b1    = (const float*)d_in[4];
    const float* W2    = (const float*)d_in[5];
    const float* b2    = (const float*)d_in[6];
    const float* Wc    = (const float*)d_in[7];
    const float* bc    = (const float*)d_in[8];
    float* out = (float*)d_out;

    // Workspace layout (byte offsets):
    //   0         sums    8192 f                 (32768 B)
    //   32768     counts  256 f                  (1024 B)
    //   33792     cnt     NB*PB u16              (195500 B) -> end 229292
    //   229296    binned  NB*PB*SEGCAP u32       (12512000 B) -> end 12741296
    //   12741296  y16     (N_NODES+1)*32 half    (3200064 B)   total ~16 MB
    char* ws = (char*)d_ws;
    float*          sums   = (float*)ws;
    float*          counts = (float*)(ws + 32768);
    unsigned short* cnt    = (unsigned short*)(ws + 33792);
    unsigned int*   binned = (unsigned int*)(ws + 229296);
    __half*         y16    = (__half*)(ws + 12741296);

    k_front<<<PB + XBLK, 256, 0, stream>>>(
        x, W1, y16, ei, ei + N_EDGES, binned, cnt, sums, counts);

    k_agg<<<NB, 1024, 0, stream>>>(binned, cnt, y16, batch,
                                   b1, W2, b2, sums, counts);

    k_out<<<1, 256, 0, stream>>>(sums, counts, Wc, bc, out);
}

// Round 12
// 122.999 us; speedup vs baseline: 1.1381x; 1.0846x over previous
//
#include <hip/hip_runtime.h>
#include <hip/hip_fp16.h>

#define N_NODES 50000
#define N_EDGES 800000
#define N_GRAPHS 256
#define D_FEAT 96
#define HIDDEN 32

#define NB 196        // bins: bin = dst >> 8 (256 nodes/bin)
#define PB 500        // partition blocks
#define PCHUNK 1600   // 500 * 1600 = 800000 exactly
#define SEGCAP 32     // per-(block,bin) segment capacity (Poisson mean 8.2, max~21)
#define NLOAD 16      // ceil(PB*SEGCAP/1024) staged loads in k_agg
#define GWIN 16       // pooled-graph LDS window per 256-node bin
#define LCAP 6400     // per-bin edge-list capacity (mean ~4081, 8 sigma)
#define XT 64         // nodes per xw1 tile block
#define XBLK 782      // ceil(50000/64)
#define XS_STRIDE 97  // padded LDS row stride (conflict-free lane=node reads)
#define DUMMY_NODE N_NODES   // extra zeroed y16 row for list padding

// ---------------------------------------------------------------------------
// Kernel A: blocks 0..PB-1 partition edges (int4, ILP-4) into per-(block,bin)
// segments; blocks PB.. compute y16 = fp16(x @ W1) + init chores.
// (byte-identical to the twice-verified round-9 version)
__global__ void __launch_bounds__(256)
k_front(const float* __restrict__ x, const float* __restrict__ W1,
        __half* __restrict__ y16,
        const int* __restrict__ src, const int* __restrict__ dst,
        unsigned int* __restrict__ binned, unsigned short* __restrict__ cnt,
        float* __restrict__ sums, float* __restrict__ counts) {
    __shared__ __align__(16) char smem[26656];   // union: hcur | xs
    int blk = blockIdx.x;
    int tid = threadIdx.x;
    if (blk < PB) {
        int* hcur = (int*)smem;
        for (int i = tid; i < NB; i += 256) hcur[i] = 0;
        __syncthreads();

        int e0 = blk * PCHUNK, e1 = e0 + PCHUNK;
        for (int it = 0; it < PCHUNK; it += 1024) {
            int e = e0 + it + tid * 4;
            if (e < e1) {
                int4 s4 = *(const int4*)&src[e];
                int4 d4 = *(const int4*)&dst[e];
                unsigned w0 = (unsigned)s4.x | ((unsigned)(d4.x & 255) << 16);
                unsigned w1 = (unsigned)s4.y | ((unsigned)(d4.y & 255) << 16);
                unsigned w2 = (unsigned)s4.z | ((unsigned)(d4.z & 255) << 16);
                unsigned w3 = (unsigned)s4.w | ((unsigned)(d4.w & 255) << 16);
                int b0 = d4.x >> 8, b1 = d4.y >> 8, b2 = d4.z >> 8, b3 = d4.w >> 8;
                int p0 = atomicAdd(&hcur[b0], 1);
                int p1 = atomicAdd(&hcur[b1], 1);
                int p2 = atomicAdd(&hcur[b2], 1);
                int p3 = atomicAdd(&hcur[b3], 1);
                if (p0 < SEGCAP) binned[((size_t)b0 * PB + blk) * SEGCAP + p0] = w0;
                if (p1 < SEGCAP) binned[((size_t)b1 * PB + blk) * SEGCAP + p1] = w1;
                if (p2 < SEGCAP) binned[((size_t)b2 * PB + blk) * SEGCAP + p2] = w2;
                if (p3 < SEGCAP) binned[((size_t)b3 * PB + blk) * SEGCAP + p3] = w3;
            }
        }
        __syncthreads();

        for (int i = tid; i < NB; i += 256) {
            int c = hcur[i]; if (c > SEGCAP) c = SEGCAP;
            cnt[i * PB + blk] = (unsigned short)c;
        }
    } else {
        float* xs = (float*)smem;                   // XT * XS_STRIDE floats
        int xb = blk - PB;
        int n0 = xb * XT;
        int nn = N_NODES - n0; if (nn > XT) nn = XT;

        // folded init chores (these blocks run before k_agg)
        int gid = xb * 256 + tid;
        if (gid < N_GRAPHS * HIDDEN) sums[gid] = 0.f;
        if (gid < N_GRAPHS) counts[gid] = 0.f;
        if (xb == 0 && tid < HIDDEN)
            y16[(size_t)DUMMY_NODE * HIDDEN + tid] = __float2half(0.f);

        const float4* xsrc = (const float4*)(x + (size_t)n0 * D_FEAT);
        int nf4 = nn * (D_FEAT / 4);                // up to 1536
        for (int idx = tid; idx < nf4; idx += 256) {
            int ln = (idx * 2731) >> 16;            // idx / 24 for idx < 1536
            int k4 = idx - ln * 24;
            float4 v = xsrc[idx];
            float* dp = &xs[ln * XS_STRIDE + k4 * 4];
            dp[0] = v.x; dp[1] = v.y; dp[2] = v.z; dp[3] = v.w;
        }
        __syncthreads();

        int lane = tid & 63;                        // node within tile
        int f0 = (tid >> 6) << 3;                   // wave-uniform feature base
        f0 = __builtin_amdgcn_readfirstlane(f0);    // force SGPR

        if (lane < nn) {
            const float* xr = &xs[lane * XS_STRIDE];
            const float4* W1v = (const float4*)W1;  // row k = 8 float4s
            float acc[8];
#pragma unroll
            for (int j = 0; j < 8; ++j) acc[j] = 0.f;
#pragma unroll
            for (int k = 0; k < D_FEAT; ++k) {
                float xv = xr[k];                   // LDS, conflict-free (stride 97)
                float4 wa = W1v[k * 8 + (f0 >> 2)];
                float4 wb = W1v[k * 8 + (f0 >> 2) + 1];
                acc[0] = fmaf(xv, wa.x, acc[0]);
                acc[1] = fmaf(xv, wa.y, acc[1]);
                acc[2] = fmaf(xv, wa.z, acc[2]);
                acc[3] = fmaf(xv, wa.w, acc[3]);
                acc[4] = fmaf(xv, wb.x, acc[4]);
                acc[5] = fmaf(xv, wb.y, acc[5]);
                acc[6] = fmaf(xv, wb.z, acc[6]);
                acc[7] = fmaf(xv, wb.w, acc[7]);
            }
            __half2 h01 = __floats2half2_rn(acc[0], acc[1]);
            __half2 h23 = __floats2half2_rn(acc[2], acc[3]);
            __half2 h45 = __floats2half2_rn(acc[4], acc[5]);
            __half2 h67 = __floats2half2_rn(acc[6], acc[7]);
            float4 pack;
            pack.x = __uint_as_float(*(const unsigned*)&h01);
            pack.y = __uint_as_float(*(const unsigned*)&h23);
            pack.z = __uint_as_float(*(const unsigned*)&h45);
            pack.w = __uint_as_float(*(const unsigned*)&h67);
            *(float4*)&y16[(size_t)(n0 + lane) * HIDDEN + f0] = pack;  // 16B/lane
        }
    }
}

// ---------------------------------------------------------------------------
// Kernel B: round-9 verified structure (reg-staged pack -> scan -> counting
// sort). ONLY the gather/MLP/pool loop changed: half2 lanes (16 lanes/edge,
// 4B/lane) -> half the gather instructions, double edges in flight, half the
// serial node depth per group (64 groups x 4 nodes).
__global__ void __launch_bounds__(1024)
k_agg(const unsigned int* __restrict__ binned, const unsigned short* __restrict__ cnt,
      const __half* __restrict__ y16, const int* __restrict__ batch,
      const float* __restrict__ b1, const float* __restrict__ W2,
      const float* __restrict__ b2,
      float* __restrict__ sums, float* __restrict__ counts) {
    __shared__ unsigned int list[LCAP];        // 25.6 KB packed (src|dstlo<<16)
    __shared__ unsigned short list2[LCAP];     // 12.8 KB node-sorted src (8-padded)
    __shared__ unsigned int sA[512], sB[512];  // 4 KB scan ping-pong
    __shared__ unsigned short cs[PB];
    __shared__ unsigned int sOfs[PB];
    __shared__ unsigned int ncnt[256];
    __shared__ unsigned int offs[257];
    __shared__ unsigned int cur[256];
    __shared__ float w2s[HIDDEN * HIDDEN];     // 4 KB
    __shared__ float accs[GWIN * HIDDEN];      // 2 KB
    __shared__ float cntsl[GWIN];

    int tid = threadIdx.x;
    int bin = blockIdx.x;
    if (tid < 256) ncnt[tid] = 0;
    w2s[tid] = W2[tid];                        // 1024 threads cover exactly
    if (tid < GWIN * HIDDEN) accs[tid] = 0.f;
    if (tid < GWIN) cntsl[tid] = 0.f;
    if (tid < 512) {
        unsigned c = (tid < PB) ? (unsigned)cnt[bin * PB + tid] : 0u;
        if (tid < PB) cs[tid] = (unsigned short)c;
        sA[tid] = c;
    }

    // issue the pack loads IMMEDIATELY so 16 independent loads fly under the scan
    const unsigned int* ebase = binned + (size_t)bin * PB * SEGCAP;
    unsigned u[NLOAD];
#pragma unroll
    for (int j = 0; j < NLOAD; ++j)
        u[j] = ebase[tid + j * 1024];              // unconditional (slack mapped)
    __syncthreads();

    // inclusive scan over 512 (9 steps)
    unsigned *ps = sA, *pd = sB;
    for (int d = 1; d < 512; d <<= 1) {
        if (tid < 512) { unsigned v = ps[tid]; if (tid >= d) v += ps[tid - d]; pd[tid] = v; }
        __syncthreads();
        unsigned* t = ps; ps = pd; pd = t;
    }
    if (tid < PB) sOfs[tid] = tid ? ps[tid - 1] : 0u;
    int ecount = (int)ps[PB - 1];
    if (ecount > LCAP) ecount = LCAP;
    __syncthreads();

    // predicated LDS scatter of the staged registers
#pragma unroll
    for (int j = 0; j < NLOAD; ++j) {
        int idx = tid + j * 1024;
        if (idx < PB * SEGCAP) {                   // compile-time true for j<15
            int s = idx >> 5;                      // SEGCAP = 32
            int i = idx & 31;
            if (i < (int)cs[s]) {
                unsigned pos = sOfs[s] + i;
                if (pos < LCAP) list[pos] = u[j];
            }
        }
    }
    __syncthreads();

    // per-node histogram
    for (int e = tid; e < ecount; e += 1024)
        atomicAdd(&ncnt[list[e] >> 16], 1u);
    __syncthreads();

    // exclusive scan over 8-PADDED node counts
    if (tid < 256) sA[tid] = (ncnt[tid] + 7u) & ~7u;
    __syncthreads();
    ps = sA; pd = sB;
    for (int d = 1; d < 256; d <<= 1) {
        if (tid < 256) { unsigned v = ps[tid]; if (tid >= d) v += ps[tid - d]; pd[tid] = v; }
        __syncthreads();
        unsigned* t = ps; ps = pd; pd = t;
    }
    if (tid < 256) {
        offs[tid + 1] = ps[tid];
        cur[tid] = tid ? ps[tid - 1] : 0u;
    }
    if (tid == 0) offs[0] = 0;
    __syncthreads();

    // place src ids
    for (int e = tid; e < ecount; e += 1024) {
        unsigned p = list[e];
        unsigned pos = atomicAdd(&cur[p >> 16], 1u);
        if (pos < LCAP) list2[pos] = (unsigned short)(p & 0xFFFFu);
    }
    __syncthreads();
    // pad each node's list to its 8-multiple with the dummy (zero) row
    if (tid < 256) {
        unsigned i0 = cur[tid], i1 = offs[tid + 1];
        for (unsigned i = i0; i < i1 && i < LCAP; ++i)
            list2[i] = (unsigned short)DUMMY_NODE;
    }
    __syncthreads();

    // ---- gather/MLP/pool: half2 lanes (16 lanes/edge, 4B/lane) ----
    int node0 = bin << 8;
    int nn = N_NODES - node0; if (nn > 256) nn = 256;
    int g  = tid >> 4;     // group 0..63 (four per wave64)
    int f2 = tid & 15;     // feature-pair lane (features 2f2, 2f2+1)
    int gfirst = batch[node0];
    const __half2* y16h2 = (const __half2*)y16;

    for (int ln = g * 4; ln < g * 4 + 4; ++ln) {
        if (ln >= nn) break;
        int node = node0 + ln;
        float2 acc = __half22float2(y16h2[(size_t)node * 16 + f2]);  // self term
        int j = offs[ln], jend = offs[ln + 1];                       // both %8 == 0
        for (; j < jend; j += 8) {                 // 8 edges, 8 half2 loads in flight
            ushort4 qa = *(const ushort4*)&list2[j];
            ushort4 qb = *(const ushort4*)&list2[j + 4];
            float2 a0 = __half22float2(y16h2[(size_t)qa.x * 16 + f2]);
            float2 a1 = __half22float2(y16h2[(size_t)qa.y * 16 + f2]);
            float2 a2 = __half22float2(y16h2[(size_t)qa.z * 16 + f2]);
            float2 a3 = __half22float2(y16h2[(size_t)qa.w * 16 + f2]);
            float2 a4 = __half22float2(y16h2[(size_t)qb.x * 16 + f2]);
            float2 a5 = __half22float2(y16h2[(size_t)qb.y * 16 + f2]);
            float2 a6 = __half22float2(y16h2[(size_t)qb.z * 16 + f2]);
            float2 a7 = __half22float2(y16h2[(size_t)qb.w * 16 + f2]);
            acc.x += ((a0.x + a1.x) + (a2.x + a3.x)) + ((a4.x + a5.x) + (a6.x + a7.x));
            acc.y += ((a0.y + a1.y) + (a2.y + a3.y)) + ((a4.y + a5.y) + (a6.y + a7.y));
        }

        float h1x = fmaxf(acc.x + b1[2 * f2],     0.f);
        float h1y = fmaxf(acc.y + b1[2 * f2 + 1], 0.f);
        float h2x = b2[2 * f2], h2y = b2[2 * f2 + 1];
#pragma unroll
        for (int kk = 0; kk < 16; ++kk) {          // h1[2kk],h1[2kk+1] via shuffles
            float ex = __shfl(h1x, kk, 16);
            float ey = __shfl(h1y, kk, 16);
            h2x = fmaf(ex, w2s[(2 * kk) * HIDDEN + 2 * f2],     h2x);
            h2y = fmaf(ex, w2s[(2 * kk) * HIDDEN + 2 * f2 + 1], h2y);
            h2x = fmaf(ey, w2s[(2 * kk + 1) * HIDDEN + 2 * f2],     h2x);
            h2y = fmaf(ey, w2s[(2 * kk + 1) * HIDDEN + 2 * f2 + 1], h2y);
        }
        float hx = fmaxf(h2x, 0.f);
        float hy = fmaxf(h2y, 0.f);

        int gr = batch[node];
        int b = gr - gfirst;
        if (b < GWIN) {
            atomicAdd(&accs[b * HIDDEN + 2 * f2],     hx);
            atomicAdd(&accs[b * HIDDEN + 2 * f2 + 1], hy);
            if (f2 == 0) atomicAdd(&cntsl[b], 1.f);
        } else {
            atomicAdd(&sums[(size_t)gr * HIDDEN + 2 * f2],     hx);
            atomicAdd(&sums[(size_t)gr * HIDDEN + 2 * f2 + 1], hy);
            if (f2 == 0) atomicAdd(&counts[gr], 1.f);
        }
    }
    __syncthreads();

    for (int i = tid; i < GWIN * HIDDEN; i += 1024) {
        float v = accs[i];
        if (v != 0.f) atomicAdd(&sums[(size_t)gfirst * HIDDEN + i], v);
    }
    if (tid < GWIN) {
        float c = cntsl[tid];
        if (c != 0.f) atomicAdd(&counts[gfirst + tid], c);
    }
}

// ---------------------------------------------------------------------------
// Kernel C: out[g] = (sums[g]/max(counts[g],1)) @ Wc + bc
__global__ void k_out(const float* __restrict__ sums, const float* __restrict__ counts,
                      const float* __restrict__ Wc, const float* __restrict__ bc,
                      float* __restrict__ out) {
    int g = threadIdx.x;
    if (g >= N_GRAPHS) return;
    float inv = 1.f / fmaxf(counts[g], 1.f);
    float o0 = bc[0], o1 = bc[1];
#pragma unroll
    for (int k = 0; k < HIDDEN; ++k) {
        float p = sums[(size_t)g * HIDDEN + k] * inv;
        o0 = fmaf(p, Wc[k * 2 + 0], o0);
        o1 = fmaf(p, Wc[k * 2 + 1], o1);
    }
    out[g * 2 + 0] = o0;
    out[g * 2 + 1] = o1;
}

// ---------------------------------------------------------------------------
extern "C" void kernel_launch(void* const* d_in, const int* in_sizes, int n_in,
                              void* d_out, int out_size, void* d_ws, size_t ws_size,
                              hipStream_t stream) {
    const float* x     = (const float*)d_in[0];
    const int*   ei    = (const int*)d_in[1];   // [2, N_EDGES]: src row then dst row
    const int*   batch = (const int*)d_in[2];
    const float* W1    = (const float*)d_in[3];
    const float* b1    = (const float*)d_in[4];
    const float* W2    = (const float*)d_in[5];
    const float* b2    = (const float*)d_in[6];
    const float* Wc    = (const float*)d_in[7];
    const float* bc    = (const float*)d_in[8];
    float* out = (float*)d_out;

    // Workspace layout (byte offsets):
    //   0         sums    8192 f                 (32768 B)
    //   32768     counts  256 f                  (1024 B)
    //   33792     cnt     NB*PB u16              (196000 B) -> end 229792
    //   229792    binned  NB*PB*SEGCAP u32       (12544000 B) -> end 12773792
    //   12773792  y16     (N_NODES+1)*32 half    (3200064 B)   total ~16 MB
    char* ws = (char*)d_ws;
    float*          sums   = (float*)ws;
    float*          counts = (float*)(ws + 32768);
    unsigned short* cnt    = (unsigned short*)(ws + 33792);
    unsigned int*   binned = (unsigned int*)(ws + 229792);
    __half*         y16    = (__half*)(ws + 12773792);

    k_front<<<PB + XBLK, 256, 0, stream>>>(
        x, W1, y16, ei, ei + N_EDGES, binned, cnt, sums, counts);

    k_agg<<<NB, 1024, 0, stream>>>(binned, cnt, y16, batch,
                                   b1, W2, b2, sums, counts);

    k_out<<<1, 256, 0, stream>>>(sums, counts, Wc, bc, out);
}